// Round 7
// baseline (27.335 us; speedup 1.0000x reference)
//
#include <hip/hip_runtime.h>

// Problem constants (from reference)
constexpr int BATCH    = 4096;
constexpr int L        = 3968;   // L_SB == M2IR_TRUNC
constexpr int LM_IN    = 4800;   // mesh2ir input row stride
constexpr int HALF     = 40;     // WIN // 2
constexpr int RAMP_CAP = 200;
constexpr int NV4      = L / 4;  // 992 float4 groups per row
constexpr int TPB      = 512;    // 992 = 512 + 480 -> 2 unrolled steps
constexpr int ITER     = 2;

typedef float f32x4 __attribute__((ext_vector_type(4)));

__global__ __launch_bounds__(TPB)
void crossfade_kernel(const float* __restrict__ sb,       // [B, L]
                      const float* __restrict__ m2,       // [B, LM_IN]
                      const float* __restrict__ latent,   // [B, 10]
                      const int*   __restrict__ o_sb,     // [B]
                      const int*   __restrict__ o_m,      // [B]
                      float*       __restrict__ out,      // [B, L]
                      float*       __restrict__ out_org)  // [B]
{
    const int b   = blockIdx.x;
    const int tid = threadIdx.x;

    const int ss = max(o_sb[b] - HALF, 0);
    const int ms = max(o_m[b]  - HALF, 0);
    const int until = min(L - ss, L - ms);

    const float l0 = latent[b * 10 + 0];
    const float l1 = latent[b * 10 + 1];
    const float l2 = latent[b * 10 + 2];
    const float vol = (l0 * l1) * l2;
    const int mp = (int)floorf((0.002f * sqrtf(vol)) * 16000.0f);

    const bool active = until > mp;

    // Regions: [0,rampStart)=sb  [rampStart,rampEnd)=blend
    //          [rampEnd,tailEnd)=m2  [tailEnd,L)=sb
    int rampStart, rampEnd, tailEnd;
    float denom = 1.0f;
    if (active) {
        const int ramp = min(until - mp, RAMP_CAP);   // >= 1
        rampStart = ss + mp;
        rampEnd   = rampStart + ramp;
        tailEnd   = ss + until;
        denom     = (float)max(ramp - 1, 1);
    } else {
        rampStart = rampEnd = tailEnd = L;
    }

    const int off = ms - ss;      // m_idx = j + off
    const int sh  = off & 3;      // wave-uniform misalignment

    const float* __restrict__ sbrow  = sb  + (size_t)b * L;
    const float* __restrict__ m2row  = m2  + (size_t)b * LM_IN;
    float*       __restrict__ outrow = out + (size_t)b * L;

    // ---- Phase 1: issue ALL loads (up to 6 x 16B in flight per thread) ----
    f32x4 sv[ITER], va[ITER], vb[ITER];
    bool  nsb[ITER], nm[ITER], ok[ITER];

#pragma unroll
    for (int k = 0; k < ITER; ++k) {
        const int c4 = tid + k * TPB;
        const bool valid = (c4 < NV4);
        const int j0 = c4 * 4;
        nsb[k] = valid && ((j0 < rampEnd) || (j0 + 3 >= tailEnd));
        nm[k]  = valid && ((j0 + 3 >= rampStart) && (j0 < tailEnd));
        sv[k] = f32x4{0.f, 0.f, 0.f, 0.f};
        va[k] = f32x4{0.f, 0.f, 0.f, 0.f};
        vb[k] = f32x4{0.f, 0.f, 0.f, 0.f};
        ok[k] = false;
        if (nsb[k]) {
            sv[k] = reinterpret_cast<const f32x4*>(sbrow)[c4];
        }
        if (nm[k]) {
            const int base = j0 + off - sh;   // aligned-down
            // base < 0 only possible for k==0 (j0 <= 6) — rare straddle,
            // handled in phase 2.
            if (k > 0 || base >= 0) {
                ok[k] = true;
                va[k] = reinterpret_cast<const f32x4*>(m2row)[base >> 2];
                vb[k] = reinterpret_cast<const f32x4*>(m2row)[(base >> 2) + 1];
            }
        }
    }

    // ---- Phase 2: select + store ----
#pragma unroll
    for (int k = 0; k < ITER; ++k) {
        const int c4 = tid + k * TPB;
        if (c4 >= NV4) continue;
        const int j0 = c4 * 4;

        f32x4 mv = {0.f, 0.f, 0.f, 0.f};
        if (nm[k]) {
            if (ok[k]) {
                switch (sh) {                 // wave-uniform branch
                case 0:  mv = va[k]; break;
                case 1:  mv = f32x4{va[k].y, va[k].z, va[k].w, vb[k].x}; break;
                case 2:  mv = f32x4{va[k].z, va[k].w, vb[k].x, vb[k].y}; break;
                default: mv = f32x4{va[k].w, vb[k].x, vb[k].y, vb[k].z}; break;
                }
            } else {
                // Rare row-start straddle (k==0, tid<=1): guarded scalars.
                const int idx0 = j0 + off;
                if (idx0 + 0 >= 0) mv.x = m2row[idx0 + 0];
                if (idx0 + 1 >= 0) mv.y = m2row[idx0 + 1];
                if (idx0 + 2 >= 0) mv.z = m2row[idx0 + 2];
                if (idx0 + 3 >= 0) mv.w = m2row[idx0 + 3];
            }
        }

        f32x4 r;
#pragma unroll
        for (int u = 0; u < 4; ++u) {
            const int j = j0 + u;
            float o;
            if (j < rampStart || j >= tailEnd) {
                o = sv[k][u];
            } else if (j >= rampEnd) {
                o = mv[u];
            } else {
                const float kk = (float)(j - rampStart);
                const float w  = fminf(fmaxf(kk / denom, 0.0f), 1.0f);
                o = sv[k][u] * (1.0f - w) + mv[u] * w;
            }
            r[u] = o;
        }
        __builtin_nontemporal_store(r, reinterpret_cast<f32x4*>(outrow) + c4);
    }

    if (tid == 0) {
        out_org[b] = (float)HALF;
    }
}

extern "C" void kernel_launch(void* const* d_in, const int* in_sizes, int n_in,
                              void* d_out, int out_size, void* d_ws, size_t ws_size,
                              hipStream_t stream) {
    const float* sb     = (const float*)d_in[0];
    const float* m2     = (const float*)d_in[1];
    const float* latent = (const float*)d_in[2];
    const int*   o_sb   = (const int*)d_in[3];
    const int*   o_m    = (const int*)d_in[4];

    float* out     = (float*)d_out;
    float* out_org = out + (size_t)BATCH * L;

    crossfade_kernel<<<BATCH, TPB, 0, stream>>>(sb, m2, latent, o_sb, o_m,
                                                out, out_org);
}

// Round 8
// 26.069 us; speedup vs baseline: 1.0485x; 1.0485x over previous
//
#include <hip/hip_runtime.h>

// Problem constants (from reference)
constexpr int BATCH    = 4096;
constexpr int L        = 3968;   // L_SB == M2IR_TRUNC
constexpr int LM_IN    = 4800;   // mesh2ir input row stride
constexpr int HALF     = 40;     // WIN // 2
constexpr int RAMP_CAP = 200;
constexpr int PARTS    = 2;      // blocks per row (halves block granularity)
constexpr int NV4      = L / 4;  // 992 float4 groups per row
constexpr int GPB      = NV4 / PARTS;  // 496 groups per block

typedef float f32x4 __attribute__((ext_vector_type(4)));

__global__ __launch_bounds__(256)
void crossfade_kernel(const float* __restrict__ sb,       // [B, L]
                      const float* __restrict__ m2,       // [B, LM_IN]
                      const float* __restrict__ latent,   // [B, 10]
                      const int*   __restrict__ o_sb,     // [B]
                      const int*   __restrict__ o_m,      // [B]
                      float*       __restrict__ out,      // [B, L]
                      float*       __restrict__ out_org)  // [B]
{
    const int b    = blockIdx.x >> 1;      // row
    const int part = blockIdx.x & 1;       // which half of the row

    const int ss = max(o_sb[b] - HALF, 0);
    const int ms = max(o_m[b]  - HALF, 0);
    const int until = min(L - ss, L - ms);

    const float l0 = latent[b * 10 + 0];
    const float l1 = latent[b * 10 + 1];
    const float l2 = latent[b * 10 + 2];
    const float vol = (l0 * l1) * l2;
    const int mp = (int)floorf((0.002f * sqrtf(vol)) * 16000.0f);

    const bool active = until > mp;

    // Regions: [0,rampStart)=sb  [rampStart,rampEnd)=blend
    //          [rampEnd,tailEnd)=m2  [tailEnd,L)=sb
    int rampStart, rampEnd, tailEnd;
    float denom = 1.0f;
    if (active) {
        const int ramp = min(until - mp, RAMP_CAP);   // >= 1
        rampStart = ss + mp;
        rampEnd   = rampStart + ramp;
        tailEnd   = ss + until;
        denom     = (float)max(ramp - 1, 1);
    } else {
        rampStart = rampEnd = tailEnd = L;            // everything = sb
    }

    const int off = ms - ss;      // per-row constant shift: m_idx = j + off
    const int sh  = off & 3;      // wave-uniform misalignment

    const float* __restrict__ sbrow  = sb  + (size_t)b * L;
    const float* __restrict__ m2row  = m2  + (size_t)b * LM_IN;
    float*       __restrict__ outrow = out + (size_t)b * L;

    const int c4begin = part * GPB;
    const int c4end   = c4begin + GPB;

    for (int c4 = c4begin + threadIdx.x; c4 < c4end; c4 += 256) {
        const int j0 = c4 * 4;

        const bool needSb = (j0 < rampEnd) || (j0 + 3 >= tailEnd);
        const bool needM  = (j0 + 3 >= rampStart) && (j0 < tailEnd);

        f32x4 sv = {0.f, 0.f, 0.f, 0.f};
        if (needSb) {
            sv = reinterpret_cast<const f32x4*>(sbrow)[c4];
        }

        f32x4 mv = {0.f, 0.f, 0.f, 0.f};
        if (needM) {
            const int idx0 = j0 + off;       // m index of element 0
            const int base = idx0 - sh;      // aligned-down, multiple of 4
            if (base >= 0) {
                const f32x4 va = reinterpret_cast<const f32x4*>(m2row)[base >> 2];
                const f32x4 vb = reinterpret_cast<const f32x4*>(m2row)[(base >> 2) + 1];
                switch (sh) {                // wave-uniform branch
                case 0:  mv = va; break;
                case 1:  mv = f32x4{va.y, va.z, va.w, vb.x}; break;
                case 2:  mv = f32x4{va.z, va.w, vb.x, vb.y}; break;
                default: mv = f32x4{va.w, vb.x, vb.y, vb.z}; break;
                }
            } else {
                // Rare edge: group straddles m-row start. Guarded scalar loads.
                if (idx0 + 0 >= 0) mv.x = m2row[idx0 + 0];
                if (idx0 + 1 >= 0) mv.y = m2row[idx0 + 1];
                if (idx0 + 2 >= 0) mv.z = m2row[idx0 + 2];
                if (idx0 + 3 >= 0) mv.w = m2row[idx0 + 3];
            }
        }

        f32x4 r;
#pragma unroll
        for (int u = 0; u < 4; ++u) {
            const int j = j0 + u;
            float o;
            if (j < rampStart || j >= tailEnd) {
                o = sv[u];
            } else if (j >= rampEnd) {
                o = mv[u];
            } else {
                const float k = (float)(j - rampStart);
                const float w = fminf(fmaxf(k / denom, 0.0f), 1.0f);
                o = sv[u] * (1.0f - w) + mv[u] * w;
            }
            r[u] = o;
        }

        __builtin_nontemporal_store(r, reinterpret_cast<f32x4*>(outrow) + c4);
    }

    if (threadIdx.x == 0 && part == 0) {
        out_org[b] = (float)HALF;
    }
}

extern "C" void kernel_launch(void* const* d_in, const int* in_sizes, int n_in,
                              void* d_out, int out_size, void* d_ws, size_t ws_size,
                              hipStream_t stream) {
    const float* sb     = (const float*)d_in[0];
    const float* m2     = (const float*)d_in[1];
    const float* latent = (const float*)d_in[2];
    const int*   o_sb   = (const int*)d_in[3];
    const int*   o_m    = (const int*)d_in[4];

    float* out     = (float*)d_out;
    float* out_org = out + (size_t)BATCH * L;

    crossfade_kernel<<<BATCH * PARTS, 256, 0, stream>>>(sb, m2, latent,
                                                        o_sb, o_m, out, out_org);
}